// Round 1
// baseline (3837.303 us; speedup 1.0000x reference)
//
#include <hip/hip_runtime.h>
#include <cstdint>
#include <cstddef>

// Problem constants (fixed by the reference instance)
#define B_  1024
#define S_  200
#define N_  100000
#define D_  512
#define K_  50
constexpr float LN_EPS = 1e-5f;

// ---------------------------------------------------------------------------
// helpers
// ---------------------------------------------------------------------------
__device__ inline unsigned okey(float f) {
    // order-preserving map float -> unsigned (total order, NaN-free data)
    unsigned u = __float_as_uint(f);
    return (u & 0x80000000u) ? ~u : (u | 0x80000000u);
}

// ---------------------------------------------------------------------------
// 1) masked mean-pool over sequence -> user_rep [B, D]
// ---------------------------------------------------------------------------
__global__ __launch_bounds__(256) void k_pool(const int* __restrict__ ids,
                                              const float* __restrict__ E,
                                              float* __restrict__ user_rep) {
    __shared__ int sid[S_];
    int b = blockIdx.x;
    int t = threadIdx.x;
    for (int s = t; s < S_; s += 256) sid[s] = ids[b * S_ + s];
    __syncthreads();
    float a0 = 0.f, a1 = 0.f;
    int cnt = 0;
    for (int s = 0; s < S_; ++s) {
        int id = sid[s];               // uniform across block
        if (id != 0) {
            const float* row = E + (size_t)(id - 1) * D_;
            a0 += row[t];
            a1 += row[t + 256];
            ++cnt;
        }
    }
    float denom = fmaxf((float)cnt, 1.f);
    user_rep[b * D_ + t]       = a0 / denom;
    user_rep[b * D_ + t + 256] = a1 / denom;
}

// ---------------------------------------------------------------------------
// 2) fp32 NT GEMM: C[M,N] = A[M,K] * B[N,K]^T (+ bias[n])
//    BM=BN=64, BK=16, 256 threads, 4x4 micro-tile per thread.
//    blockIdx.x = M-tile (fast) so consecutive blocks share the B tile in L2.
// ---------------------------------------------------------------------------
#define BM 64
#define BN 64
#define BK 16

__global__ __launch_bounds__(256) void k_gemm_nt(const float* __restrict__ A,
                                                 const float* __restrict__ Bm,
                                                 const float* __restrict__ bias,
                                                 float* __restrict__ C,
                                                 int M, int N, int K) {
    __shared__ float As[BK][BM];
    __shared__ float Bs[BK][BN];
    int tid = threadIdx.x;
    int tx = tid & 15, ty = tid >> 4;
    int m0 = blockIdx.x * BM;
    int n0 = blockIdx.y * BN;

    float acc[4][4] = {};

    int r  = tid >> 2;          // 0..63 : tile row this thread stages
    int kk = (tid & 3) * 4;     // 0,4,8,12 : k-offset within tile

    for (int k0 = 0; k0 < K; k0 += BK) {
        // stage A tile (transposed into As[k][m])
        {
            const float4 av = *reinterpret_cast<const float4*>(
                &A[(size_t)(m0 + r) * K + k0 + kk]);
            As[kk + 0][r] = av.x;
            As[kk + 1][r] = av.y;
            As[kk + 2][r] = av.z;
            As[kk + 3][r] = av.w;
        }
        // stage B tile (transposed into Bs[k][n]), zero-fill past N
        {
            float4 bv = make_float4(0.f, 0.f, 0.f, 0.f);
            int n = n0 + r;
            if (n < N)
                bv = *reinterpret_cast<const float4*>(
                    &Bm[(size_t)n * K + k0 + kk]);
            Bs[kk + 0][r] = bv.x;
            Bs[kk + 1][r] = bv.y;
            Bs[kk + 2][r] = bv.z;
            Bs[kk + 3][r] = bv.w;
        }
        __syncthreads();
#pragma unroll
        for (int k = 0; k < BK; ++k) {
            float4 a4 = *reinterpret_cast<const float4*>(&As[k][ty * 4]);
            float4 b4 = *reinterpret_cast<const float4*>(&Bs[k][tx * 4]);
            float a[4] = {a4.x, a4.y, a4.z, a4.w};
            float bb[4] = {b4.x, b4.y, b4.z, b4.w};
#pragma unroll
            for (int i = 0; i < 4; ++i)
#pragma unroll
                for (int j = 0; j < 4; ++j)
                    acc[i][j] = fmaf(a[i], bb[j], acc[i][j]);
        }
        __syncthreads();
    }

    // epilogue
    int n = n0 + tx * 4;
    float4 bv = make_float4(0.f, 0.f, 0.f, 0.f);
    if (bias) {
        if (n + 3 < N) {
            bv = *reinterpret_cast<const float4*>(&bias[n]);
        } else {
            float tmp[4] = {0.f, 0.f, 0.f, 0.f};
            for (int j = 0; j < 4; ++j)
                if (n + j < N) tmp[j] = bias[n + j];
            bv = make_float4(tmp[0], tmp[1], tmp[2], tmp[3]);
        }
    }
#pragma unroll
    for (int i = 0; i < 4; ++i) {
        int m = m0 + ty * 4 + i;
        float4 v = make_float4(acc[i][0] + bv.x, acc[i][1] + bv.y,
                               acc[i][2] + bv.z, acc[i][3] + bv.w);
        if (n + 3 < N) {
            *reinterpret_cast<float4*>(&C[(size_t)m * N + n]) = v;
        } else {
            float tmp[4] = {v.x, v.y, v.z, v.w};
            for (int j = 0; j < 4; ++j)
                if (n + j < N) C[(size_t)m * N + n + j] = tmp[j];
        }
    }
}

// ---------------------------------------------------------------------------
// 3a) per-row 2048-bin histogram over ordered-key top 11 bits ->
//     threshold bin for top-K
// ---------------------------------------------------------------------------
__global__ __launch_bounds__(256) void k_topk_hist(const float* __restrict__ scores,
                                                   int* __restrict__ bin_info) {
    __shared__ int hist[4][2048];   // per-wave copies to cut atomic contention
    int b = blockIdx.x, t = threadIdx.x, w = t >> 6;
    for (int i = t; i < 4 * 2048; i += 256) (&hist[0][0])[i] = 0;
    __syncthreads();
    const float4* row4 =
        reinterpret_cast<const float4*>(scores + (size_t)b * N_);
    for (int i = t; i < N_ / 4; i += 256) {
        float4 v = row4[i];
        atomicAdd(&hist[w][okey(v.x) >> 21], 1);
        atomicAdd(&hist[w][okey(v.y) >> 21], 1);
        atomicAdd(&hist[w][okey(v.z) >> 21], 1);
        atomicAdd(&hist[w][okey(v.w) >> 21], 1);
    }
    __syncthreads();
    for (int i = t; i < 2048; i += 256)
        hist[0][i] += hist[1][i] + hist[2][i] + hist[3][i];
    __syncthreads();
    if (t == 0) {
        int cum = 0, bin = 2047;
        for (; bin > 0; --bin) {
            int h = hist[0][bin];
            if (cum + h >= K_) break;
            cum += h;
        }
        bin_info[b * 2]     = bin;  // threshold bin
        bin_info[b * 2 + 1] = cum;  // count strictly above threshold bin
    }
}

// ---------------------------------------------------------------------------
// 3b) collect candidates >= threshold bin, exact-rank select top-K indices
// ---------------------------------------------------------------------------
#define MAXC 4096
__global__ __launch_bounds__(256) void k_topk_collect(const float* __restrict__ scores,
                                                      const int* __restrict__ bin_info,
                                                      int* __restrict__ top_idx) {
    __shared__ float cval[MAXC];
    __shared__ int   cidx[MAXC];
    __shared__ int   cnt;
    int b = blockIdx.x, t = threadIdx.x;
    if (t == 0) cnt = 0;
    __syncthreads();
    unsigned tbin = (unsigned)bin_info[b * 2];
    const float4* row4 =
        reinterpret_cast<const float4*>(scores + (size_t)b * N_);
    for (int i = t; i < N_ / 4; i += 256) {
        float4 v = row4[i];
        float vv[4] = {v.x, v.y, v.z, v.w};
#pragma unroll
        for (int j = 0; j < 4; ++j) {
            if ((okey(vv[j]) >> 21) >= tbin) {
                int p = atomicAdd(&cnt, 1);
                if (p < MAXC) { cval[p] = vv[j]; cidx[p] = i * 4 + j; }
            }
        }
    }
    __syncthreads();
    int C = min(cnt, MAXC);
    for (int ci = t; ci < C; ci += 256) {
        float v = cval[ci];
        int id  = cidx[ci];
        int rnk = 0;
        for (int j = 0; j < C; ++j) {
            float vj = cval[j];
            rnk += (vj > v) || (vj == v && cidx[j] < id);
        }
        if (rnk < K_) top_idx[b * K_ + rnk] = id;  // ranks 0..K-1 unique
    }
}

// ---------------------------------------------------------------------------
// 4) retrieved = mean of top-K embeddings [B, D]
// ---------------------------------------------------------------------------
__global__ __launch_bounds__(256) void k_retrieved(const int* __restrict__ top_idx,
                                                   const float* __restrict__ E,
                                                   float* __restrict__ retrieved) {
    __shared__ int sidx[K_];
    int b = blockIdx.x, t = threadIdx.x;
    if (t < K_) sidx[t] = top_idx[b * K_ + t];
    __syncthreads();
    float a0 = 0.f, a1 = 0.f;
    for (int i = 0; i < K_; ++i) {
        const float* row = E + (size_t)sidx[i] * D_;
        a0 += row[t];
        a1 += row[t + 256];
    }
    retrieved[b * D_ + t]       = a0 * (1.f / K_);
    retrieved[b * D_ + t + 256] = a1 * (1.f / K_);
}

// ---------------------------------------------------------------------------
// 5) fusion_in = concat(user_rep, retrieved) [B, 2D]
// ---------------------------------------------------------------------------
__global__ __launch_bounds__(256) void k_concat(const float* __restrict__ u,
                                                const float* __restrict__ r,
                                                float* __restrict__ fin) {
    int b = blockIdx.x, t = threadIdx.x;
    const float4* u4 = reinterpret_cast<const float4*>(u + (size_t)b * D_);
    const float4* r4 = reinterpret_cast<const float4*>(r + (size_t)b * D_);
    float4* f4 = reinterpret_cast<float4*>(fin + (size_t)b * 2 * D_);
    if (t < 128) f4[t] = u4[t];
    else         f4[t] = r4[t - 128];
}

// ---------------------------------------------------------------------------
// 6) gate = sigmoid(gate_raw); fused = g*u + (1-g)*r; LayerNorm -> out
// ---------------------------------------------------------------------------
__global__ __launch_bounds__(256) void k_fuse_ln(const float* __restrict__ graw,
                                                 const float* __restrict__ u,
                                                 const float* __restrict__ r,
                                                 const float* __restrict__ gamma,
                                                 const float* __restrict__ beta,
                                                 float* __restrict__ outp) {
    int b = blockIdx.x, t = threadIdx.x;
    float f0, f1;
    {
        float g0 = 1.f / (1.f + expf(-graw[b * D_ + t]));
        f0 = g0 * u[b * D_ + t] + (1.f - g0) * r[b * D_ + t];
        float g1 = 1.f / (1.f + expf(-graw[b * D_ + t + 256]));
        f1 = g1 * u[b * D_ + t + 256] + (1.f - g1) * r[b * D_ + t + 256];
    }
    float s  = f0 + f1;
    float s2 = f0 * f0 + f1 * f1;
#pragma unroll
    for (int o = 32; o > 0; o >>= 1) {
        s  += __shfl_down(s, o);
        s2 += __shfl_down(s2, o);
    }
    __shared__ float ws1[4], ws2[4];
    int w = t >> 6, lane = t & 63;
    if (lane == 0) { ws1[w] = s; ws2[w] = s2; }
    __syncthreads();
    float ts  = ws1[0] + ws1[1] + ws1[2] + ws1[3];
    float ts2 = ws2[0] + ws2[1] + ws2[2] + ws2[3];
    float mu  = ts / (float)D_;
    float var = ts2 / (float)D_ - mu * mu;
    float rstd = rsqrtf(var + LN_EPS);
    outp[b * D_ + t]       = (f0 - mu) * rstd * gamma[t]       + beta[t];
    outp[b * D_ + t + 256] = (f1 - mu) * rstd * gamma[t + 256] + beta[t + 256];
}

// ---------------------------------------------------------------------------
// launch
// ---------------------------------------------------------------------------
extern "C" void kernel_launch(void* const* d_in, const int* in_sizes, int n_in,
                              void* d_out, int out_size, void* d_ws, size_t ws_size,
                              hipStream_t stream) {
    const int*   ids   = (const int*)d_in[0];
    const float* E     = (const float*)d_in[1];
    const float* fW    = (const float*)d_in[2];
    const float* fb    = (const float*)d_in[3];
    const float* gamma = (const float*)d_in[4];
    const float* beta  = (const float*)d_in[5];
    const float* pW    = (const float*)d_in[6];
    const float* pb    = (const float*)d_in[7];
    float* out = (float*)d_out;   // used as scores buffer, overwritten by logits

    // workspace carve (~12.5 MB)
    float* wsf       = (float*)d_ws;
    float* user_rep  = wsf;                       // B*D
    float* retrieved = user_rep  + B_ * D_;       // B*D
    float* fusion_in = retrieved + B_ * D_;       // B*2D
    float* gate_raw  = fusion_in + B_ * 2 * D_;   // B*D
    float* fused     = gate_raw  + B_ * D_;       // B*D
    int*   bin_info  = (int*)(fused + B_ * D_);   // 2*B
    int*   top_idx   = bin_info + 2 * B_;         // B*K

    // 1) user_rep
    k_pool<<<B_, 256, 0, stream>>>(ids, E, user_rep);

    // 2) scores = user_rep . E^T  -> d_out
    dim3 gs(B_ / BM, (N_ + BN - 1) / BN);
    k_gemm_nt<<<gs, 256, 0, stream>>>(user_rep, E, nullptr, out, B_, N_, D_);

    // 3) top-50 per row
    k_topk_hist<<<B_, 256, 0, stream>>>(out, bin_info);
    k_topk_collect<<<B_, 256, 0, stream>>>(out, bin_info, top_idx);

    // 4) retrieved
    k_retrieved<<<B_, 256, 0, stream>>>(top_idx, E, retrieved);

    // 5) gated fusion: concat -> GEMM(+bias) -> sigmoid/fuse/LN
    k_concat<<<B_, 256, 0, stream>>>(user_rep, retrieved, fusion_in);
    dim3 gg(B_ / BM, D_ / BN);
    k_gemm_nt<<<gg, 256, 0, stream>>>(fusion_in, fW, fb, gate_raw, B_, D_, 2 * D_);
    k_fuse_ln<<<B_, 256, 0, stream>>>(gate_raw, user_rep, retrieved, gamma, beta, fused);

    // 6) logits = fused . proj_W^T + proj_b -> d_out (overwrites scores)
    k_gemm_nt<<<gs, 256, 0, stream>>>(fused, pW, pb, out, B_, N_, D_);
}